// Round 15
// baseline (66.155 us; speedup 1.0000x reference)
//
#include <hip/hip_runtime.h>
#include <hip/hip_bf16.h>
#include <cstdint>

// LearnableUpsamplingLayer: polyphase decomposition + bf16 MFMA.
// B=8, T=16384, C=64, F=64, filter=5, leaky 0.3.
// out[b,2t+p,f] = sum_tap M_p[tap][c,f] * x[t-1+tap, c]   (x outside [0,T) = 0)
// Even p=0: 3 taps; odd p=1: 4 taps. Frames 0,1 get a correction (the
// polyphase substitution leaks a (1-w)*x[0] term through blend[-1]).
//
// R15: SINGLE KERNEL (tests the last surviving hypothesis: two-launch graph
// overhead + inter-kernel drain is the residual above the ~15us memory
// floor). No cross-block data: each wave computes its OWN 14 weight
// fragments inline (16 sigmoids + 80 scalar ck loads + ~300 VALU, once per
// block, hidden under staging); q==0 blocks compute the boundary correction
// inline. Grid 1024 x 256 (4 blocks/CU), 2 segments of 64 pairs per block,
// single 9.9KB LDS buffer, 3 __syncthreads. Main body = proven R9 structure:
// cooperative bf16 staging, direct ds_read_b128 fragments, operand-swapped
// MFMA (W=A -> each thread owns 4 consecutive filters, dwordx4 stores).

#define T_ 16384
#define TWO_T 32768
#define NFR 67             // staged frames per segment: ps-1 .. ps+65
#define XSTRIDE 72         // ushorts per frame row (144 B; benign banking)

typedef __bf16 bf16x8 __attribute__((ext_vector_type(8)));
typedef __bf16 bf16x4 __attribute__((ext_vector_type(4)));
typedef float  f32x4  __attribute__((ext_vector_type(4)));
typedef unsigned short u16x8 __attribute__((ext_vector_type(8)));

__device__ __forceinline__ float sigmoidf_(float z) {
    return 1.0f / (1.0f + expf(-z));
}

__global__ __launch_bounds__(256, 4) void lu_kernel(
        const float* __restrict__ x,
        const float* __restrict__ iw,
        const float* __restrict__ ck,
        const float* __restrict__ bias,
        float* __restrict__ out) {
    __shared__ __align__(16) unsigned short xl[NFR * XSTRIDE];   // 9,648 B

    const int bid  = blockIdx.x;        // 0..1023
    const int b    = bid >> 7;          // batch
    const int q    = bid & 127;
    const int p0   = q << 7;            // 128 time-pairs per block
    const int tid  = threadIdx.x;
    const int lane = tid & 63;
    const int wv   = tid >> 6;          // wave = filter tile
    const int hi   = lane >> 4;
    const int col  = lane & 15;         // time-pair within window
    const int n    = (wv << 4) + col;   // this lane's filter column

    const float* xb = x + (size_t)b * T_ * 64;

    // ---- stage segment 0 (VMEM issued first; weight VALU overlaps) ----
#pragma unroll
    for (int it = 0; it < 5; ++it) {
        int idx = it * 256 + tid;
        if (idx < NFR * 16) {
            int j  = idx >> 4;
            int c4 = (idx & 15) << 2;
            int gf = p0 - 1 + j;
            float4 v = make_float4(0.f, 0.f, 0.f, 0.f);
            if ((unsigned)gf < (unsigned)T_)
                v = *(const float4*)(xb + ((size_t)gf << 6) + c4);
            bf16x4 pk;
            pk[0] = (__bf16)v.x; pk[1] = (__bf16)v.y;
            pk[2] = (__bf16)v.z; pk[3] = (__bf16)v.w;
            *(bf16x4*)(xl + j * XSTRIDE + c4) = pk;
        }
    }

    // ---- inline per-wave weight fragments (once per block) ----
    // frag (ks=tap*2+ch): lane elem i = M[tap][c=ch*32+hi*8+i][n]
    float wl[8], wh[8];
#pragma unroll
    for (int i = 0; i < 8; i += 4) {
        float4 a  = *(const float4*)(iw + (hi << 3) + i);
        float4 c2 = *(const float4*)(iw + 32 + (hi << 3) + i);
        wl[i] = sigmoidf_(a.x);  wl[i+1] = sigmoidf_(a.y);
        wl[i+2] = sigmoidf_(a.z); wl[i+3] = sigmoidf_(a.w);
        wh[i] = sigmoidf_(c2.x); wh[i+1] = sigmoidf_(c2.y);
        wh[i+2] = sigmoidf_(c2.z); wh[i+3] = sigmoidf_(c2.w);
    }
    bf16x8 We[6], Wo[8];
#pragma unroll
    for (int ch = 0; ch < 2; ++ch)
#pragma unroll
        for (int i = 0; i < 8; ++i) {
            int c = (ch << 5) + (hi << 3) + i;
            const float* ckc = ck + (size_t)c * 64 + n;   // ck[(k*64+c)*64+n]
            float k0 = ckc[0];
            float k1 = ckc[4096];
            float k2 = ckc[8192];
            float k3 = ckc[12288];
            float k4 = ckc[16384];
            float w  = ch ? wh[i] : wl[i];
            float u  = 1.f - w;
            We[ch][i]     = (__bf16)(k0 + w * k1);
            We[2 + ch][i] = (__bf16)(u * k1 + k2 + w * k3);
            We[4 + ch][i] = (__bf16)(u * k3 + k4);
            Wo[ch][i]     = (__bf16)(w * k0);
            Wo[2 + ch][i] = (__bf16)(u * k0 + k1 + w * k2);
            Wo[4 + ch][i] = (__bf16)(u * k2 + k3 + w * k4);
            Wo[6 + ch][i] = (__bf16)(u * k4);
        }

    const float4 bias4 = *(const float4*)(bias + (wv << 4) + (hi << 2));

    // ---- inline boundary correction (q==0 blocks only; all threads
    //      compute their 4-filter slice, only col==0 applies it) ----
    f32x4 corrE = {0.f, 0.f, 0.f, 0.f}, corrO = {0.f, 0.f, 0.f, 0.f};
    if (q == 0) {
        const int fo = (wv << 4) + (hi << 2);
#pragma unroll 4
        for (int c = 0; c < 64; ++c) {
            float w = sigmoidf_(iw[c]);
            float g = (1.f - w) * xb[c];            // x[b,0,c]
            const float4 k1v = *(const float4*)(ck + 4096 + c * 64 + fo);
            const float4 k0v = *(const float4*)(ck + c * 64 + fo);
            corrE[0] += k1v.x * g; corrE[1] += k1v.y * g;
            corrE[2] += k1v.z * g; corrE[3] += k1v.w * g;
            corrO[0] += k0v.x * g; corrO[1] += k0v.y * g;
            corrO[2] += k0v.z * g; corrO[3] += k0v.w * g;
        }
    }

    __syncthreads();

    // ---- two segments of 64 pairs each ----
#pragma unroll
    for (int s = 0; s < 2; ++s) {
        const int ps = p0 + (s << 6);

        if (s == 1) {
            // restage buffer for segment 1
#pragma unroll
            for (int it = 0; it < 5; ++it) {
                int idx = it * 256 + tid;
                if (idx < NFR * 16) {
                    int j  = idx >> 4;
                    int c4 = (idx & 15) << 2;
                    int gf = ps - 1 + j;
                    float4 v = make_float4(0.f, 0.f, 0.f, 0.f);
                    if ((unsigned)gf < (unsigned)T_)
                        v = *(const float4*)(xb + ((size_t)gf << 6) + c4);
                    bf16x4 pk;
                    pk[0] = (__bf16)v.x; pk[1] = (__bf16)v.y;
                    pk[2] = (__bf16)v.z; pk[3] = (__bf16)v.w;
                    *(bf16x4*)(xl + j * XSTRIDE + c4) = pk;
                }
            }
            __syncthreads();
        }

#pragma unroll
        for (int w = 0; w < 4; ++w) {
            f32x4 accE = {0.f, 0.f, 0.f, 0.f};
            f32x4 accO = {0.f, 0.f, 0.f, 0.f};
#pragma unroll
            for (int tap = 0; tap < 4; ++tap) {
                int r = (w << 4) + col + tap;       // row 0..66
                bf16x8 x0 = __builtin_bit_cast(bf16x8,
                    *(const u16x8*)(xl + r * XSTRIDE + (hi << 3)));
                bf16x8 x1 = __builtin_bit_cast(bf16x8,
                    *(const u16x8*)(xl + r * XSTRIDE + 32 + (hi << 3)));
                if (tap < 3) {
                    accE = __builtin_amdgcn_mfma_f32_16x16x32_bf16(We[tap * 2],     x0, accE, 0, 0, 0);
                    accE = __builtin_amdgcn_mfma_f32_16x16x32_bf16(We[tap * 2 + 1], x1, accE, 0, 0, 0);
                }
                accO = __builtin_amdgcn_mfma_f32_16x16x32_bf16(Wo[tap * 2],     x0, accO, 0, 0, 0);
                accO = __builtin_amdgcn_mfma_f32_16x16x32_bf16(Wo[tap * 2 + 1], x1, accO, 0, 0, 0);
            }

            // ---- boundary correction (output frames 0,1 of each batch) ----
            if (((q | s | w) == 0) && col == 0) {
                accE[0] -= corrE[0]; accE[1] -= corrE[1];
                accE[2] -= corrE[2]; accE[3] -= corrE[3];
                accO[0] -= corrO[0]; accO[1] -= corrO[1];
                accO[2] -= corrO[2]; accO[3] -= corrO[3];
            }

            // ---- epilogue: bias + leaky_relu, one dwordx4 store per phase ----
            const int tl = ps + (w << 4) + col;
            const size_t fbase = ((size_t)b * TWO_T + ((size_t)tl << 1)) * 64
                               + (wv << 4) + (hi << 2);
            float4 vE, vO;
            {
                float e0 = accE[0] + bias4.x, e1 = accE[1] + bias4.y,
                      e2 = accE[2] + bias4.z, e3 = accE[3] + bias4.w;
                vE.x = e0 >= 0.f ? e0 : 0.3f * e0;
                vE.y = e1 >= 0.f ? e1 : 0.3f * e1;
                vE.z = e2 >= 0.f ? e2 : 0.3f * e2;
                vE.w = e3 >= 0.f ? e3 : 0.3f * e3;
                float o0 = accO[0] + bias4.x, o1 = accO[1] + bias4.y,
                      o2 = accO[2] + bias4.z, o3 = accO[3] + bias4.w;
                vO.x = o0 >= 0.f ? o0 : 0.3f * o0;
                vO.y = o1 >= 0.f ? o1 : 0.3f * o1;
                vO.z = o2 >= 0.f ? o2 : 0.3f * o2;
                vO.w = o3 >= 0.f ? o3 : 0.3f * o3;
            }
            *(float4*)(out + fbase)      = vE;   // even frame 2*tl
            *(float4*)(out + fbase + 64) = vO;   // odd frame 2*tl+1
        }

        if (s == 0) __syncthreads();   // all ds_reads of seg 0 done before
                                       // seg-1 staging overwrites the buffer
    }
}

extern "C" void kernel_launch(void* const* d_in, const int* in_sizes, int n_in,
                              void* d_out, int out_size, void* d_ws, size_t ws_size,
                              hipStream_t stream) {
    (void)in_sizes; (void)n_in; (void)out_size; (void)d_ws; (void)ws_size;
    const float* x    = (const float*)d_in[0];
    const float* iw   = (const float*)d_in[1];
    const float* ck   = (const float*)d_in[2];
    const float* bias = (const float*)d_in[3];
    float* out = (float*)d_out;

    lu_kernel<<<1024, 256, 0, stream>>>(x, iw, ck, bias, out);
}

// Round 16
// 39.977 us; speedup vs baseline: 1.6548x; 1.6548x over previous
//
#include <hip/hip_runtime.h>
#include <hip/hip_bf16.h>
#include <cstdint>

// LearnableUpsamplingLayer: polyphase decomposition + bf16 MFMA.
// B=8, T=16384, C=64, F=64, filter=5, leaky 0.3.
// out[b,2t+p,f] = sum_tap M_p[tap][c,f] * x[t-1+tap, c]   (x outside [0,T) = 0)
// Even p=0: 3 taps; odd p=1: 4 taps. Frames 0,1 get a precomputed correction
// (the polyphase substitution leaks a (1-w)*x[0] term through blend[-1]).
//
// R16: PHASE-SPLIT WAVES. 512-thread blocks: waves 0-3 = even phase (6
// weight frags, 24 VGPR), waves 4-7 = odd phase (8 frags, 32 VGPR). Per-wave
// VGPR ~60 -> __launch_bounds__(512,8) (<=64 cap) -> 32 waves/CU: DOUBLE the
// occupancy of every ~32us variant (whose 56-reg weight table pinned them at
// <=16 waves/CU -- the m69 64-VGPR cliff). Block-shared f32 staging via
// global_load_lds (zero staging VGPRs, XOR-involution swizzle both sides,
// one __syncthreads provides the vmcnt drain). Operand-swapped MFMA ->
// each thread owns 4 consecutive filters of one frame -> 1 dwordx4 store
// per window per wave.

#define T_ 16384
#define TWO_T 32768
#define NFR 68             // staged frames: p0-1 .. p0+66 (need 67)

typedef __bf16 bf16x8 __attribute__((ext_vector_type(8)));
typedef float  f32x4  __attribute__((ext_vector_type(4)));
typedef unsigned short u16x8 __attribute__((ext_vector_type(8)));

__device__ __forceinline__ float sigmoidf_(float z) {
    return 1.0f / (1.0f + expf(-z));
}

__device__ __forceinline__ unsigned short f2bf(float f) {
    union { float f; uint32_t u; } v; v.f = f;
    uint32_t u = v.u;
    return (unsigned short)((u + 0x7FFFu + ((u >> 16) & 1u)) >> 16);
}

// ---------------- prep: 64 blocks x 64 threads (proven, unchanged).
// Blocks 0..55: the 7 polyphase matrices as packed bf16 fragments:
//   frag (phase, ks, nt): lane l elem i = M[tap=ks>>1][c=(ks&1)*32+(l>>4)*8+i]
//                                          [f=nt*16+(l&15)]
// Blocks 56..63: b = fi-56; corr[b][{E,O}][f] = sum_c K[{1,0}][c][f]*(1-w_c)*x[b,0,c]
// Block 63 additionally zeroes the 256B zero-pad (OOB redirect target).
__global__ void lu_prep_kernel(const float* __restrict__ iw,
                               const float* __restrict__ ck,
                               const float* __restrict__ x,
                               unsigned short* __restrict__ bp,
                               float* __restrict__ corrf,
                               float* __restrict__ zp) {
    int fi = blockIdx.x;
    int l  = threadIdx.x;
    if (fi < 56) {
        int phase, ks, nt;
        if (fi < 24) { phase = 0; ks = fi >> 2; nt = fi & 3; }
        else         { phase = 1; ks = (fi - 24) >> 2; nt = (fi - 24) & 3; }
        int tap = ks >> 1;
        int n   = nt * 16 + (l & 15);
        int c0  = ((ks & 1) << 5) + ((l >> 4) << 3);
        u16x8 pk;
#pragma unroll
        for (int i = 0; i < 8; ++i) {
            int c = c0 + i;
            float w = sigmoidf_(iw[c]);
            float v;
            #define CK(k) ck[((k) * 64 + c) * 64 + n]
            if (phase == 0) {
                if (tap == 0)      v = CK(0) + w * CK(1);
                else if (tap == 1) v = (1.f - w) * CK(1) + CK(2) + w * CK(3);
                else               v = (1.f - w) * CK(3) + CK(4);
            } else {
                if (tap == 0)      v = w * CK(0);
                else if (tap == 1) v = (1.f - w) * CK(0) + CK(1) + w * CK(2);
                else if (tap == 2) v = (1.f - w) * CK(2) + CK(3) + w * CK(4);
                else               v = (1.f - w) * CK(4);
            }
            #undef CK
            pk[i] = f2bf(v);
        }
        *(u16x8*)(bp + (((size_t)fi * 64) + l) * 8) = pk;
    } else {
        int b = fi - 56;
        int f = l;
        float cE = 0.f, cO = 0.f;
#pragma unroll
        for (int c = 0; c < 64; ++c) {
            float w = sigmoidf_(iw[c]);
            float g = (1.f - w) * x[(size_t)b * T_ * 64 + c];
            cE += ck[(64 + c) * 64 + f] * g;   // K1
            cO += ck[c * 64 + f] * g;          // K0
        }
        corrf[b * 128 + f]      = cE;
        corrf[b * 128 + 64 + f] = cO;
        if (fi == 63) zp[l] = 0.f;             // 64 floats = 256 B zero pad
    }
}

// ---------------- main ----------------
__device__ __forceinline__ void gload16(const float* g, float* l) {
    __builtin_amdgcn_global_load_lds(
        (const __attribute__((address_space(1))) uint32_t*)g,
        (__attribute__((address_space(3))) uint32_t*)l, 16, 0, 0);
}

__device__ __forceinline__ bf16x8 pack8(f32x4 a, f32x4 b) {
    bf16x8 r;
    r[0] = (__bf16)a[0]; r[1] = (__bf16)a[1];
    r[2] = (__bf16)a[2]; r[3] = (__bf16)a[3];
    r[4] = (__bf16)b[0]; r[5] = (__bf16)b[1];
    r[6] = (__bf16)b[2]; r[7] = (__bf16)b[3];
    return r;
}

__global__ __launch_bounds__(512, 8) void lu_main_kernel(
        const float* __restrict__ x,
        const unsigned short* __restrict__ bp,
        const float* __restrict__ corrf,
        const float* __restrict__ bias,
        const float* __restrict__ zp,
        float* __restrict__ out) {
    __shared__ __align__(16) float xl[NFR * 64];   // 17,408 B, block-shared

    const int bid  = blockIdx.x;        // 0..2047
    const int b    = bid >> 8;
    const int q    = bid & 255;
    const int p0   = q << 6;            // 64 time-pairs per block
    const int tid  = threadIdx.x;
    const int lane = tid & 63;
    const int wv   = tid >> 6;          // 0..7
    const int ph   = wv >> 2;           // 0 = even phase, 1 = odd phase
    const int ft   = wv & 3;            // filter tile (16 filters)

    const float* xb = x + (size_t)b * T_ * 64;

    // ---- this wave's weight fragments (6 for E, 8 for O; <=32 VGPR) ----
    bf16x8 W[8];
    const int fb0 = ph ? 24 : 0;
#pragma unroll
    for (int ks = 0; ks < 8; ++ks)
        if (ph || ks < 6)
            W[ks] = __builtin_bit_cast(bf16x8,
                *(const u16x8*)(bp + (((size_t)(fb0 + ks * 4 + ft)) * 64 + lane) * 8));

    const int hi   = lane >> 4;
    const int hi2  = hi << 1;
    const int col  = lane & 15;         // time-pair within window
    const float4 bias4 = *(const float4*)(bias + (ft << 4) + (hi << 2));

    // ---- cooperative DMA staging: frames p0-1 .. p0+66 -> rows 0..67.
    // 17 groups of 4 rows; wave wv stages groups G = wv, wv+8, wv+16 (<17).
    // Lane: row j = 4G + (lane>>4), chunk slot s = lane&15; global source
    // chunk = s ^ (j&7) (XOR involution; reads undo it). OOB -> zero pad.
#pragma unroll
    for (int g = 0; g < 3; ++g) {
        int G = wv + (g << 3);
        if (G < 17) {
            int j0 = G << 2;
            int j  = j0 + (lane >> 4);
            int gf = p0 - 1 + j;
            int ch = (lane & 15) ^ (j & 7);
            const float* gp = ((unsigned)gf < (unsigned)T_)
                            ? xb + ((size_t)gf << 6) + (ch << 2)
                            : zp + (ch << 2);
            gload16(gp, xl + j0 * 64);
        }
    }

    // ---- one barrier: implied vmcnt(0) drain orders DMAs before ds_reads --
    __syncthreads();

    const char* xwb = (const char*)xl;

#pragma unroll
    for (int w = 0; w < 4; ++w) {
        f32x4 acc = {0.f, 0.f, 0.f, 0.f};
#pragma unroll
        for (int tap = 0; tap < 4; ++tap) {
            if (ph || tap < 3) {
                int j    = (w << 4) + col + tap;        // row 0..66
                int key  = j & 7;
                int off0 = (j << 8) + ((hi2 ^ key) << 4);
                f32x4 qa = *(const f32x4*)(xwb + off0);
                f32x4 qb = *(const f32x4*)(xwb + (off0 ^ 16));
                bf16x8 x0 = pack8(qa, qb);              // channels 0-31 half
                acc = __builtin_amdgcn_mfma_f32_16x16x32_bf16(W[tap * 2], x0, acc, 0, 0, 0);
                f32x4 qc = *(const f32x4*)(xwb + off0 + 128);
                f32x4 qd = *(const f32x4*)(xwb + ((off0 + 128) ^ 16));
                bf16x8 x1 = pack8(qc, qd);              // channels 32-63 half
                acc = __builtin_amdgcn_mfma_f32_16x16x32_bf16(W[tap * 2 + 1], x1, acc, 0, 0, 0);
            }
        }

        // ---- boundary correction (output frames 0,1 of each batch) ----
        if (((q | w) == 0) && col == 0) {
            const float4 c4 = *(const float4*)(corrf + b * 128 + (ph << 6)
                                               + (ft << 4) + (hi << 2));
            acc[0] -= c4.x; acc[1] -= c4.y; acc[2] -= c4.z; acc[3] -= c4.w;
        }

        // ---- epilogue: bias + leaky_relu, one dwordx4 store ----
        const int tl = p0 + (w << 4) + col;
        const size_t fbase = ((size_t)b * TWO_T + (size_t)((tl << 1) + ph)) * 64
                           + (ft << 4) + (hi << 2);
        float4 v;
        {
            float e0 = acc[0] + bias4.x, e1 = acc[1] + bias4.y,
                  e2 = acc[2] + bias4.z, e3 = acc[3] + bias4.w;
            v.x = e0 >= 0.f ? e0 : 0.3f * e0;
            v.y = e1 >= 0.f ? e1 : 0.3f * e1;
            v.z = e2 >= 0.f ? e2 : 0.3f * e2;
            v.w = e3 >= 0.f ? e3 : 0.3f * e3;
        }
        *(float4*)(out + fbase) = v;
    }
}

extern "C" void kernel_launch(void* const* d_in, const int* in_sizes, int n_in,
                              void* d_out, int out_size, void* d_ws, size_t ws_size,
                              hipStream_t stream) {
    (void)in_sizes; (void)n_in; (void)out_size; (void)ws_size;
    const float* x    = (const float*)d_in[0];
    const float* iw   = (const float*)d_in[1];
    const float* ck   = (const float*)d_in[2];
    const float* bias = (const float*)d_in[3];
    float* out = (float*)d_out;
    unsigned short* bp = (unsigned short*)d_ws;            // 57,344 B
    float* corrf = (float*)((char*)d_ws + 57344);          // 4,096 B
    float* zp    = (float*)((char*)d_ws + 61440);          //   256 B zeros

    lu_prep_kernel<<<64, 64, 0, stream>>>(iw, ck, x, bp, corrf, zp);
    lu_main_kernel<<<2048, 512, 0, stream>>>(x, bp, corrf, bias, zp, out);
}

// Round 17
// 32.373 us; speedup vs baseline: 2.0435x; 1.2349x over previous
//
#include <hip/hip_runtime.h>
#include <hip/hip_bf16.h>
#include <cstdint>

// LearnableUpsamplingLayer: polyphase decomposition + bf16 MFMA.
// B=8, T=16384, C=64, F=64, filter=5, leaky 0.3.
// out[b,2t+p,f] = sum_tap M_p[tap][c,f] * x[t-1+tap, c]   (x outside [0,T) = 0)
// Even p=0: 3 taps; odd p=1: 4 taps. Frames 0,1 get a precomputed correction
// (the polyphase substitution leaks a (1-w)*x[0] term through blend[-1]).
//
// R17 = R9 (proven 32.0us: f32 DMA staging + XOR involution swizzle, one
// staging barrier, resident weight table, operand-swapped MFMA) + CONTIGUOUS
// STORES via a double-buffered 2x8KB LDS out-stage. Theory: every ~32us
// variant stored 16 disjoint 64B segments per wave-instruction (col = time
// varies across lanes -> 512B stride); the fill kernel's contiguous writes
// hit 6.7 TB/s while we never exceed ~2.6. Now each window's results are
// scattered into LDS (XOR-swizzled rows, cheap) and flushed as 1KB-per-
// wave-instruction contiguous stores. Double buffer -> 1 barrier/window.

#define T_ 16384
#define TWO_T 32768
#define NFR 68             // staged frames: p0-1 .. p0+66 (need 67)

typedef __bf16 bf16x8 __attribute__((ext_vector_type(8)));
typedef float  f32x4  __attribute__((ext_vector_type(4)));
typedef unsigned short u16x8 __attribute__((ext_vector_type(8)));

__device__ __forceinline__ float sigmoidf_(float z) {
    return 1.0f / (1.0f + expf(-z));
}

__device__ __forceinline__ unsigned short f2bf(float f) {
    union { float f; uint32_t u; } v; v.f = f;
    uint32_t u = v.u;
    return (unsigned short)((u + 0x7FFFu + ((u >> 16) & 1u)) >> 16);
}

// ---------------- prep: 64 blocks x 64 threads (proven, unchanged).
__global__ void lu_prep_kernel(const float* __restrict__ iw,
                               const float* __restrict__ ck,
                               const float* __restrict__ x,
                               unsigned short* __restrict__ bp,
                               float* __restrict__ corrf,
                               float* __restrict__ zp) {
    int fi = blockIdx.x;
    int l  = threadIdx.x;
    if (fi < 56) {
        int phase, ks, nt;
        if (fi < 24) { phase = 0; ks = fi >> 2; nt = fi & 3; }
        else         { phase = 1; ks = (fi - 24) >> 2; nt = (fi - 24) & 3; }
        int tap = ks >> 1;
        int n   = nt * 16 + (l & 15);
        int c0  = ((ks & 1) << 5) + ((l >> 4) << 3);
        u16x8 pk;
#pragma unroll
        for (int i = 0; i < 8; ++i) {
            int c = c0 + i;
            float w = sigmoidf_(iw[c]);
            float v;
            #define CK(k) ck[((k) * 64 + c) * 64 + n]
            if (phase == 0) {
                if (tap == 0)      v = CK(0) + w * CK(1);
                else if (tap == 1) v = (1.f - w) * CK(1) + CK(2) + w * CK(3);
                else               v = (1.f - w) * CK(3) + CK(4);
            } else {
                if (tap == 0)      v = w * CK(0);
                else if (tap == 1) v = (1.f - w) * CK(0) + CK(1) + w * CK(2);
                else if (tap == 2) v = (1.f - w) * CK(2) + CK(3) + w * CK(4);
                else               v = (1.f - w) * CK(4);
            }
            #undef CK
            pk[i] = f2bf(v);
        }
        *(u16x8*)(bp + (((size_t)fi * 64) + l) * 8) = pk;
    } else {
        int b = fi - 56;
        int f = l;
        float cE = 0.f, cO = 0.f;
#pragma unroll
        for (int c = 0; c < 64; ++c) {
            float w = sigmoidf_(iw[c]);
            float g = (1.f - w) * x[(size_t)b * T_ * 64 + c];
            cE += ck[(64 + c) * 64 + f] * g;   // K1
            cO += ck[c * 64 + f] * g;          // K0
        }
        corrf[b * 128 + f]      = cE;
        corrf[b * 128 + 64 + f] = cO;
        if (fi == 63) zp[l] = 0.f;             // 64 floats = 256 B zero pad
    }
}

// ---------------- main ----------------
__device__ __forceinline__ void gload16(const float* g, float* l) {
    __builtin_amdgcn_global_load_lds(
        (const __attribute__((address_space(1))) uint32_t*)g,
        (__attribute__((address_space(3))) uint32_t*)l, 16, 0, 0);
}

__device__ __forceinline__ bf16x8 pack8(f32x4 a, f32x4 b) {
    bf16x8 r;
    r[0] = (__bf16)a[0]; r[1] = (__bf16)a[1];
    r[2] = (__bf16)a[2]; r[3] = (__bf16)a[3];
    r[4] = (__bf16)b[0]; r[5] = (__bf16)b[1];
    r[6] = (__bf16)b[2]; r[7] = (__bf16)b[3];
    return r;
}

__global__ __launch_bounds__(256, 4) void lu_main_kernel(
        const float* __restrict__ x,
        const unsigned short* __restrict__ bp,
        const float* __restrict__ corrf,
        const float* __restrict__ bias,
        const float* __restrict__ zp,
        float* __restrict__ out) {
    __shared__ __align__(16) float xl[NFR * 64];       // 17,408 B staging
    __shared__ __align__(16) float ol[2][32 * 64];     // 2 x 8,192 B out-stage

    const int bid  = blockIdx.x;        // 0..2047
    const int b    = bid >> 8;
    const int q    = bid & 255;
    const int p0   = q << 6;            // first time-pair (64 per block)
    const int tid  = threadIdx.x;
    const int lane = tid & 63;
    const int wv   = tid >> 6;          // wave = filter tile

    const float* xb = x + (size_t)b * T_ * 64;

    // ---- weight A-fragments + bias (oldest VMEM) ----
    bf16x8 We[6], Wo[8];
#pragma unroll
    for (int ks = 0; ks < 6; ++ks)
        We[ks] = __builtin_bit_cast(bf16x8,
            *(const u16x8*)(bp + (((size_t)(ks * 4 + wv)) * 64 + lane) * 8));
#pragma unroll
    for (int ks = 0; ks < 8; ++ks)
        Wo[ks] = __builtin_bit_cast(bf16x8,
            *(const u16x8*)(bp + (((size_t)(24 + ks * 4 + wv)) * 64 + lane) * 8));

    const int hi   = lane >> 4;
    const int hi2  = hi << 1;
    const int col  = lane & 15;         // time-pair within window
    const int f0   = (wv << 4) + (hi << 2);   // this thread's 4 filters
    const float4 bias4 = *(const float4*)(bias + f0);

    // ---- cooperative DMA staging (R9, proven): rows j=0..67 ----
#pragma unroll
    for (int g = 0; g < 5; ++g) {
        int j0 = g * 16 + (wv << 2);
        if (j0 < NFR) {
            int j  = j0 + (lane >> 4);
            int gf = p0 - 1 + j;
            int ch = (lane & 15) ^ (j & 7);
            const float* gp = ((unsigned)gf < (unsigned)T_)
                            ? xb + ((size_t)gf << 6) + (ch << 2)
                            : zp + (ch << 2);
            gload16(gp, xl + j0 * 64);
        }
    }

    __syncthreads();   // implied vmcnt(0): DMAs done before ds_reads

    const char* xwb = (const char*)xl;
    // base output frame of this block
    const size_t obase = (size_t)b * TWO_T + ((size_t)p0 << 1);

#pragma unroll
    for (int w = 0; w < 4; ++w) {
        // ---- fragments from shared staging (XOR-swizzled) + 14 MFMA ----
        f32x4 accE = {0.f, 0.f, 0.f, 0.f};
        f32x4 accO = {0.f, 0.f, 0.f, 0.f};
#pragma unroll
        for (int tap = 0; tap < 4; ++tap) {
            int j    = (w << 4) + col + tap;        // row 0..66
            int key  = j & 7;
            int off0 = (j << 8) + ((hi2 ^ key) << 4);
            f32x4 qa = *(const f32x4*)(xwb + off0);
            f32x4 qb = *(const f32x4*)(xwb + (off0 ^ 16));
            f32x4 qc = *(const f32x4*)(xwb + off0 + 128);
            f32x4 qd = *(const f32x4*)(xwb + ((off0 + 128) ^ 16));
            bf16x8 x0 = pack8(qa, qb);              // channels 0-31 half
            bf16x8 x1 = pack8(qc, qd);              // channels 32-63 half
            if (tap < 3) {
                accE = __builtin_amdgcn_mfma_f32_16x16x32_bf16(We[tap * 2],     x0, accE, 0, 0, 0);
                accE = __builtin_amdgcn_mfma_f32_16x16x32_bf16(We[tap * 2 + 1], x1, accE, 0, 0, 0);
            }
            accO = __builtin_amdgcn_mfma_f32_16x16x32_bf16(Wo[tap * 2],     x0, accO, 0, 0, 0);
            accO = __builtin_amdgcn_mfma_f32_16x16x32_bf16(Wo[tap * 2 + 1], x1, accO, 0, 0, 0);
        }

        // ---- boundary correction (output frames 0,1 of each batch) ----
        if (((q | w) == 0) && col == 0) {
            const float4 cE4 = *(const float4*)(corrf + b * 128 + f0);
            const float4 cO4 = *(const float4*)(corrf + b * 128 + 64 + f0);
            accE[0] -= cE4.x; accE[1] -= cE4.y; accE[2] -= cE4.z; accE[3] -= cE4.w;
            accO[0] -= cO4.x; accO[1] -= cO4.y; accO[2] -= cO4.z; accO[3] -= cO4.w;
        }

        // ---- bias + leaky_relu, scatter into out-staging LDS ----
        f32x4 vE, vO;
        {
            float e0 = accE[0] + bias4.x, e1 = accE[1] + bias4.y,
                  e2 = accE[2] + bias4.z, e3 = accE[3] + bias4.w;
            vE[0] = e0 >= 0.f ? e0 : 0.3f * e0;
            vE[1] = e1 >= 0.f ? e1 : 0.3f * e1;
            vE[2] = e2 >= 0.f ? e2 : 0.3f * e2;
            vE[3] = e3 >= 0.f ? e3 : 0.3f * e3;
            float o0 = accO[0] + bias4.x, o1 = accO[1] + bias4.y,
                  o2 = accO[2] + bias4.z, o3 = accO[3] + bias4.w;
            vO[0] = o0 >= 0.f ? o0 : 0.3f * o0;
            vO[1] = o1 >= 0.f ? o1 : 0.3f * o1;
            vO[2] = o2 >= 0.f ? o2 : 0.3f * o2;
            vO[3] = o3 >= 0.f ? o3 : 0.3f * o3;
        }
        {
            float* ob = &ol[w & 1][0];
            int rE = col << 1;          // even frame within window
            int rO = rE + 1;            // odd frame
            *(f32x4*)(ob + rE * 64 + (f0 ^ ((rE & 7) << 2))) = vE;
            *(f32x4*)(ob + rO * 64 + (f0 ^ ((rO & 7) << 2))) = vO;
        }

        __syncthreads();   // window w's ol writes visible; buffer (w^1) free

        // ---- flush window w: fully contiguous 1KB-per-wave-instr stores ----
        {
            const float* ob = &ol[w & 1][0];
#pragma unroll
            for (int it = 0; it < 2; ++it) {
                int c   = it * 256 + tid;          // 0..511 chunks of 16B
                int row = c >> 4;                  // frame within window 0..31
                int fc  = (c & 15) << 2;           // filter chunk
                f32x4 v = *(const f32x4*)(ob + row * 64 + (fc ^ ((row & 7) << 2)));
                *(f32x4*)(out + (obase + (size_t)(w << 5) + row) * 64 + fc) = v;
            }
        }
    }
}

extern "C" void kernel_launch(void* const* d_in, const int* in_sizes, int n_in,
                              void* d_out, int out_size, void* d_ws, size_t ws_size,
                              hipStream_t stream) {
    (void)in_sizes; (void)n_in; (void)out_size; (void)ws_size;
    const float* x    = (const float*)d_in[0];
    const float* iw   = (const float*)d_in[1];
    const float* ck   = (const float*)d_in[2];
    const float* bias = (const float*)d_in[3];
    float* out = (float*)d_out;
    unsigned short* bp = (unsigned short*)d_ws;            // 57,344 B
    float* corrf = (float*)((char*)d_ws + 57344);          // 4,096 B
    float* zp    = (float*)((char*)d_ws + 61440);          //   256 B zeros

    lu_prep_kernel<<<64, 64, 0, stream>>>(iw, ck, x, bp, corrf, zp);
    lu_main_kernel<<<2048, 256, 0, stream>>>(x, bp, corrf, bias, zp, out);
}